// Round 14
// baseline (1871.251 us; speedup 1.0000x reference)
//
#include <hip/hip_runtime.h>
#include <hip/hip_bf16.h>
#include <math.h>

// Problem constants
// x:(4,128,96,96) gate_w:(8,128,3,3) gate_bias:(8) expert_w:(8,128,128,3,3)
// expert_b:(8,128) shared_w:(128,128,3,3) shared_b:(128)  -> out:(4,128,96,96)

typedef __attribute__((ext_vector_type(8))) short short8;
typedef __attribute__((ext_vector_type(4))) float f32x4;

static __device__ __forceinline__ unsigned short f2bf(float f) {
    unsigned int u = __float_as_uint(f);
    unsigned int r = (u + 0x7FFFu + ((u >> 16) & 1u)) >> 16;
    return (unsigned short)r;
}

// ---------------------------------------------------------------------------
// Merged gate + prep kernel — byte-identical to round-13 (gate FP order
// frozen; XCD swizzle on gate tiles; prep transpose verified).
// ---------------------------------------------------------------------------
__global__ __launch_bounds__(256) void gate_prep_kernel(
    const float* __restrict__ x, const float* __restrict__ gw,
    const float* __restrict__ gb,
    const float* __restrict__ ew, const float* __restrict__ sw,
    float* __restrict__ scores, unsigned short* __restrict__ pw)
{
    __shared__ float red[4][64][8];            // gate partial sums (8 KB)
    __shared__ unsigned short lt2[9216];       // prep bounce (18 KB)

    const int t  = threadIdx.x;
    const int bx = blockIdx.x;

    if (bx >= 576) {
        // =================== prep transpose (144 blocks) ====================
        // pw chunk index: (e*9+tap)*2048 + wv*512 + kc*128 + h*64 + lane
        //   lane = lq*16+lm ; co = wv*32+h*16+lm ; k = kc*32+lq*8+d
        const int pblk = bx - 576;
        const int e  = pblk >> 4;
        const int wv = (pblk >> 2) & 3;
        const int kc = pblk & 3;
        const float* src = (e < 8) ? (ew + e * 147456) : sw;
        const float* sb2 = src + (wv * 32) * 1152 + kc * 288;

        #pragma unroll
        for (int j = 0; j < 36; ++j) {
            int i = t + j * 256;                 // 0..9215
            int co_l = i / 288;
            int r    = i - co_l * 288;           // k_l*9 + tap
            int k_l  = r / 9;
            int tap  = r - k_l * 9;
            float v = sb2[co_l * 1152 + r];
            lt2[tap * 1024 + (co_l >> 4) * 512 +
                ((k_l >> 3) * 16 + (co_l & 15)) * 8 + (k_l & 7)] = f2bf(v);
        }
        __syncthreads();

        uint4* pw16 = reinterpret_cast<uint4*>(pw);
        for (int c = t; c < 1152; c += 256) {
            int tap = c >> 7;
            int rem = c & 127;                   // h*64 + lane
            uint4 val = *reinterpret_cast<const uint4*>(&lt2[tap * 1024 + rem * 8]);
            pw16[(e * 9 + tap) * 2048 + wv * 512 + kc * 128 + rem] = val;
        }
        return;
    }

    // ======================= gate (576 blocks) ==============================
    // XCD-aware bijective tile swizzle: 72 consecutive tiles per XCD
    const int gl = (bx & 7) * 72 + (bx >> 3);
    const int g  = t >> 6;               // ci group (wave id)
    const int p  = t & 63;
    const int wt = gl % 3;
    const int h2 = (gl / 3) % 48;
    const int b  = gl / 144;
    const int h  = h2 * 2 + (p >> 5);
    const int w  = wt * 32 + (p & 31);

    int off[9]; float msk[9];
    #pragma unroll
    for (int kh = 0; kh < 3; kh++) {
        #pragma unroll
        for (int kw = 0; kw < 3; kw++) {
            int hh = h + kh - 1, ww = w + kw - 1;
            bool valid = (hh >= 0 && hh < 96 && ww >= 0 && ww < 96);
            int hc = min(max(hh, 0), 95), wc = min(max(ww, 0), 95);
            off[kh * 3 + kw] = hc * 96 + wc;
            msk[kh * 3 + kw] = valid ? 1.0f : 0.0f;
        }
    }

    // wave-uniform base (readfirstlane makes uniformity provable)
    const int gu = __builtin_amdgcn_readfirstlane(g);
    const float* xb = x + (b * 128 + gu * 32) * 9216;

    float acc[8] = {0.f,0.f,0.f,0.f,0.f,0.f,0.f,0.f};
    for (int ci = 0; ci < 32; ci++) {
        const float* xc = xb + ci * 9216;
        float xv[9];
        #pragma unroll
        for (int tap = 0; tap < 9; tap++) xv[tap] = xc[off[tap]] * msk[tap];

        // wave-uniform weight reads: cp uniform, e/tap compile-time
        //   w[ci][e*9+tap] = gw[(e*128 + gu*32+ci)*9 + tap]
        const float* cp = gw + (gu * 32 + ci) * 9;
        float wsc[72];
        #pragma unroll
        for (int e = 0; e < 8; e++)
            #pragma unroll
            for (int tap = 0; tap < 9; tap++)
                wsc[e * 9 + tap] = cp[e * 1152 + tap];

        // per-acc order (tap ascending within e, ci outer) == R1 gate order
        #pragma unroll
        for (int e = 0; e < 8; e++) {
            #pragma unroll
            for (int tap = 0; tap < 9; tap++)
                acc[e] += xv[tap] * wsc[e * 9 + tap];
        }
    }

    #pragma unroll
    for (int e = 0; e < 8; e++) red[g][p][e] = acc[e];
    __syncthreads();

    if (t < 64) {
        float s[8], bs[8];
        #pragma unroll
        for (int e = 0; e < 8; e++) {
            float v = red[0][t][e] + red[1][t][e] + red[2][t][e] + red[3][t][e];
            s[e]  = 1.0f / (1.0f + expf(-v));
            bs[e] = s[e] + gb[e];
        }
        // top-1 (ties -> lowest index, matches lax.top_k)
        int i1 = 0; float b1 = bs[0]; float w1 = s[0];
        #pragma unroll
        for (int e = 1; e < 8; e++)
            if (bs[e] > b1) { b1 = bs[e]; i1 = e; w1 = s[e]; }
        int i2 = -1; float b2 = -1e30f; float w2 = 0.f;
        #pragma unroll
        for (int e = 0; e < 8; e++)
            if (e != i1 && bs[e] > b2) { b2 = bs[e]; i2 = e; w2 = s[e]; }

        float mx = fmaxf(w1, w2);
        float e1 = expf(w1 - mx), e2 = expf(w2 - mx);
        float inv = 1.0f / (e1 + e2);
        float p1 = e1 * inv, p2 = e2 * inv;   // ROUTE_SCALE = 1

        const int hh = h2 * 2 + (t >> 5);
        const int ww = wt * 32 + (t & 31);
        int base = b * 8 * 9216 + hh * 96 + ww;
        #pragma unroll
        for (int e = 0; e < 8; e++) {
            float v = (e == i1) ? p1 : ((e == i2) ? p2 : 0.0f);
            scores[base + e * 9216] = v;
        }
    }
}

// ---------------------------------------------------------------------------
// Main v6: half-K tap-outer. Per (tap, K-half): 6 B-frags cached in regs
// (24 VGPR) feed all 9 experts -> 9x fewer LDS B-reads (972 -> 108 b128 per
// wave; the co-dominant LDS pipe collapses). Per half-step: zero-C MFMA into
// accE, then fold acc += s_e*accE (linear => exact). Bias folded at store.
// Register core: acc 24 + accE 24 + bf 24 + A-dbuf 32 = 104 (R2's spill was
// at 192). Grid/tiling/swizzle identical to R13 (768 blocks, 3/CU).
// ---------------------------------------------------------------------------
__global__ __launch_bounds__(256, 3) void moe_main_kernel(
    const float* __restrict__ x, const unsigned short* __restrict__ pw,
    const float* __restrict__ scores, const float* __restrict__ eb,
    const float* __restrict__ sb, float* __restrict__ out)
{
    __shared__ unsigned short xs[104 * 136];    // [hrow(4)*26+hcol][ci pad->136]
    __shared__ float sc[8][48];
    __shared__ float bia[9][128];

    const int t  = threadIdx.x;
    const int bx = blockIdx.x;
    // XCD-aware bijective tile swizzle (768 % 8 == 0)
    const int bl = (bx & 7) * 96 + (bx >> 3);
    const int wt = bl & 3;                 // 4 col-tiles of 24
    const int h2 = (bl >> 2) % 48;
    const int b  = bl / 192;
    const int h0 = h2 * 2, w0 = wt * 24;

    // ---- stage x patch (4 rows x 26 cols x 128 ci), fp32 -> bf16, transposed
    const float* xb = x + b * 128 * 9216;
    for (int i = t; i < 13312; i += 256) {
        int ci  = i / 104;
        int pix = i - ci * 104;            // hrow*26 + hcol
        int hrow = pix / 26;
        int hcol = pix - hrow * 26;
        int hh = h0 - 1 + hrow;
        int ww = w0 - 1 + hcol;
        float v = 0.0f;
        if (hh >= 0 && hh < 96 && ww >= 0 && ww < 96)
            v = xb[ci * 9216 + hh * 96 + ww];
        xs[pix * 136 + ci] = f2bf(v);
    }
    // ---- stage routing scores for the 48 pixels
    for (int i = t; i < 384; i += 256) {
        int e = i / 48, p = i - e * 48;
        sc[e][p] = scores[(b * 8 + e) * 9216 + (h0 + p / 24) * 96 + (w0 + p % 24)];
    }
    // ---- stage biases (experts + shared as e=8)
    for (int i = t; i < 1152; i += 256) {
        int e = i >> 7, co = i & 127;
        bia[e][co] = (e < 8) ? eb[(e << 7) + co] : sb[co];
    }
    __syncthreads();

    const int wv = t >> 6;
    const int l  = t & 63;
    const int lm = l & 15;   // m (A: co) / n (B: pixel) within frag
    const int lq = l >> 4;   // k-subgroup for A/B; row-group for D

    // per-lane B base offsets for the 3 pixel-frags (pixel = j*16+lm)
    int bofs[3];
    #pragma unroll
    for (int j = 0; j < 3; ++j) {
        const int px = j * 16 + lm;
        const int r = px / 24, c = px - r * 24;
        bofs[j] = ((r + 1) * 26 + (c + 1)) * 136 + lq * 8;
    }

    f32x4 acc[2][3], accE[2][3];
    #pragma unroll
    for (int i2 = 0; i2 < 2; i2++)
        #pragma unroll
        for (int j = 0; j < 3; j++)
            acc[i2][j] = (f32x4){0.f, 0.f, 0.f, 0.f};
    const f32x4 zero4 = (f32x4){0.f, 0.f, 0.f, 0.f};

    const uint4* pw4 = reinterpret_cast<const uint4*>(pw) + wv * 512 + l;

    short8 bf[6];            // B cache for one (tap, K-half): [kc2*3+j]
    uint4 afA[4], afB[4];    // A half-frag double buffer: [kc2*2+h]

// load 4 uint4 A-chunks for (etv = e*9+tap, half)
#define LOADFH(dst, etv, half_) {                                             \
    const uint4* _p = pw4 + (etv) * 2048 + (half_) * 256;                     \
    _Pragma("unroll")                                                         \
    for (int q = 0; q < 4; ++q) dst[q] = _p[(q >> 1) * 128 + (q & 1) * 64];   \
}

// load 6 B-frags for (tap via tofs, half)
#define LOADB(half_, tofs_) {                                                 \
    _Pragma("unroll")                                                         \
    for (int kc2 = 0; kc2 < 2; ++kc2)                                         \
        _Pragma("unroll")                                                     \
        for (int j = 0; j < 3; ++j)                                           \
            bf[kc2 * 3 + j] = *reinterpret_cast<const short8*>(               \
                &xs[bofs[j] + (tofs_) + ((half_) * 2 + kc2) * 32]);           \
}

// 12 MFMAs (zero-C start) + score fold
#define COMPUTEH(src, e_) {                                                   \
    {   const short8 a0 = *reinterpret_cast<const short8*>(&src[0]);          \
        const short8 a1 = *reinterpret_cast<const short8*>(&src[1]);          \
        _Pragma("unroll")                                                     \
        for (int j = 0; j < 3; ++j) {                                         \
            accE[0][j] = __builtin_amdgcn_mfma_f32_16x16x32_bf16(             \
                a0, bf[j], zero4, 0, 0, 0);                                   \
            accE[1][j] = __builtin_amdgcn_mfma_f32_16x16x32_bf16(             \
                a1, bf[j], zero4, 0, 0, 0);                                   \
        } }                                                                   \
    {   const short8 a0 = *reinterpret_cast<const short8*>(&src[2]);          \
        const short8 a1 = *reinterpret_cast<const short8*>(&src[3]);          \
        _Pragma("unroll")                                                     \
        for (int j = 0; j < 3; ++j) {                                         \
            accE[0][j] = __builtin_amdgcn_mfma_f32_16x16x32_bf16(             \
                a0, bf[3 + j], accE[0][j], 0, 0, 0);                          \
            accE[1][j] = __builtin_amdgcn_mfma_f32_16x16x32_bf16(             \
                a1, bf[3 + j], accE[1][j], 0, 0, 0);                          \
        } }                                                                   \
    _Pragma("unroll")                                                         \
    for (int j = 0; j < 3; ++j) {                                             \
        const float s_ = ((e_) < 8) ? sc[e_][j * 16 + lm] : 1.0f;             \
        _Pragma("unroll")                                                     \
        for (int i2 = 0; i2 < 2; ++i2)                                        \
            _Pragma("unroll")                                                 \
            for (int rr = 0; rr < 4; ++rr)                                    \
                acc[i2][j][rr] += s_ * accE[i2][j][rr];                       \
    }                                                                         \
}

#define STEPH(cur, nxt, e_, netv, nhalf) { LOADFH(nxt, netv, nhalf); COMPUTEH(cur, e_); }

    LOADFH(afA, 0, 0);
    #pragma unroll 1
    for (int tap = 0; tap < 9; ++tap) {
        const int kh = (tap >= 6) ? 2 : (tap >= 3 ? 1 : 0);
        const int kw = tap - kh * 3;
        const int tofs = (kh * 26 + kw - 27) * 136;
        const int ntap = (tap == 8) ? 0 : tap + 1;

        LOADB(0, tofs);
        STEPH(afA, afB, 0,  9 + tap, 0);
        STEPH(afB, afA, 1, 18 + tap, 0);
        STEPH(afA, afB, 2, 27 + tap, 0);
        STEPH(afB, afA, 3, 36 + tap, 0);
        STEPH(afA, afB, 4, 45 + tap, 0);
        STEPH(afB, afA, 5, 54 + tap, 0);
        STEPH(afA, afB, 6, 63 + tap, 0);
        STEPH(afB, afA, 7, 72 + tap, 0);
        STEPH(afA, afB, 8, tap, 1);          // prefetch (e0, tap, half1)
        LOADB(1, tofs);
        STEPH(afB, afA, 0,  9 + tap, 1);
        STEPH(afA, afB, 1, 18 + tap, 1);
        STEPH(afB, afA, 2, 27 + tap, 1);
        STEPH(afA, afB, 3, 36 + tap, 1);
        STEPH(afB, afA, 4, 45 + tap, 1);
        STEPH(afA, afB, 5, 54 + tap, 1);
        STEPH(afB, afA, 6, 63 + tap, 1);
        STEPH(afA, afB, 7, 72 + tap, 1);
        STEPH(afB, afA, 8, ntap, 0);         // prefetch next tap (e0, half0)
    }
#undef STEPH
#undef COMPUTEH
#undef LOADB
#undef LOADFH

    // ---- store: out = acc + (sum_e s_e*b_e + b_shared)
    float* ob = out + b * 128 * 9216;
    #pragma unroll
    for (int j = 0; j < 3; ++j) {
        const int px = j * 16 + lm;
        float se[8];
        #pragma unroll
        for (int e = 0; e < 8; ++e) se[e] = sc[e][px];
        const int hh = h0 + px / 24;
        const int ww = w0 + (px - (px / 24) * 24);
        #pragma unroll
        for (int i2 = 0; i2 < 2; ++i2)
            #pragma unroll
            for (int rr = 0; rr < 4; ++rr) {
                const int co = wv * 32 + i2 * 16 + lq * 4 + rr;
                float bt = bia[8][co];
                #pragma unroll
                for (int e = 0; e < 8; ++e) bt += se[e] * bia[e][co];
                ob[co * 9216 + hh * 96 + ww] = acc[i2][j][rr] + bt;
            }
    }
}

// ---------------------------------------------------------------------------
extern "C" void kernel_launch(void* const* d_in, const int* in_sizes, int n_in,
                              void* d_out, int out_size, void* d_ws, size_t ws_size,
                              hipStream_t stream) {
    const float* x  = (const float*)d_in[0];
    const float* gw = (const float*)d_in[1];
    const float* gb = (const float*)d_in[2];
    const float* ew = (const float*)d_in[3];
    const float* eb = (const float*)d_in[4];
    const float* sw = (const float*)d_in[5];
    const float* sb = (const float*)d_in[6];
    float* out = (float*)d_out;

    unsigned short* pw = (unsigned short*)d_ws;                  // 2,654,208 B
    float* scores = (float*)((char*)d_ws + 2654208);             // 1,179,648 B

    gate_prep_kernel<<<720, 256, 0, stream>>>(x, gw, gb, ew, sw, scores, pw);
    moe_main_kernel<<<768, 256, 0, stream>>>(x, pw, scores, eb, sb, out);
}